// Round 9
// baseline (22930.203 us; speedup 1.0000x reference)
//
#include <hip/hip_runtime.h>
#include <hip/hip_fp16.h>

#define B_ 256
#define S_ 512
#define F_ 64
#define H_ 1024
#define O_ 24
#define G_ 4096  // 4*H
#define NT_ 64   // ht' tile count (16-col tiles)
#define TPL_ 8   // timesteps per launch
#define RING_ 9  // h ring depth (>= TPL_+1: no address reuse within a launch)

typedef _Float16 half_t;
typedef _Float16 h8 __attribute__((ext_vector_type(8)));
typedef float f4 __attribute__((ext_vector_type(4)));

// ---- workspace layout (bytes) ----
#define OFF_H1 ((size_t)0)                                   // RING_*B*H halfs
#define OFF_H2 (OFF_H1 + (size_t)RING_*B_*H_*2)
#define OFF_C1 (OFF_H2 + (size_t)RING_*B_*H_*2)              // B*H f32
#define OFF_C2 (OFF_C1 + (size_t)B_*H_*4)
#define OFF_OP (OFF_C2 + (size_t)B_*H_*4)                    // out_part [64][B][O] f32
#define OFF_CNT (OFF_OP + (size_t)NT_*B_*O_*4)               // 4x8 sub-counters, 128B apart
#define ZBYTES (OFF_CNT + 4096)
#define OFF_BIAS0 (ZBYTES)
#define OFF_BIAS1 (OFF_BIAS0 + (size_t)G_*4)
#define OFF_XH    (OFF_BIAS1 + (size_t)G_*4)                 // B*S*F halfs
#define OFF_WIH0  (OFF_XH + (size_t)B_*S_*F_*2)              // packed, G*F halfs
#define OFF_WHH0  (OFF_WIH0 + (size_t)G_*F_*2)               // packed, G*H halfs
#define OFF_WIH1  (OFF_WHH0 + (size_t)G_*H_*2)
#define OFF_WHH1  (OFF_WIH1 + (size_t)G_*H_*2)
#define WS_NEEDED (OFF_WHH1 + (size_t)G_*H_*2)               // ~55 MiB

__global__ void k_bias(const float* __restrict__ bi0, const float* __restrict__ bh0,
                       const float* __restrict__ bi1, const float* __restrict__ bh1,
                       float* __restrict__ bias0, float* __restrict__ bias1) {
    int i = blockIdx.x * blockDim.x + threadIdx.x;
    if (i < G_) { bias0[i] = bi0[i] + bh0[i]; bias1[i] = bi1[i] + bh1[i]; }
}

__global__ void k_cvt(const float* __restrict__ src, half_t* __restrict__ dst, int n) {
    int i = blockIdx.x * blockDim.x + threadIdx.x;
    int stride = gridDim.x * blockDim.x;
    for (; i < n; i += stride) dst[i] = (half_t)src[i];
}

// Pack W [4H, NC*64] f32 -> fp16 MFMA-fragment order:
// dst h8 index i = (((g*32+ht)*NC + ck)*4 + j)*64 + lane, j = colhalf*2 + kshalf
__global__ void k_pack(const float* __restrict__ src, half_t* __restrict__ dst, int NC) {
    int i = blockIdx.x * blockDim.x + threadIdx.x;
    int total = 32768 * NC;          // 4*32*NC*4*64
    if (i >= total) return;
    int lane = i & 63;
    int j    = (i >> 6) & 3;
    int ck   = (i >> 8) % NC;
    int gh   = i / (256 * NC);       // g*32+ht, 0..127
    int srow = (gh >> 5) * H_ + (gh & 31) * 32 + (j >> 1) * 16 + (lane & 15);
    int scol = ck * 64 + (j & 1) * 32 + (lane >> 4) * 8;
    const float* s = src + (size_t)srow * (NC * 64) + scol;
    h8 v;
    #pragma unroll
    for (int e = 0; e < 8; ++e) v[e] = (half_t)s[e];
    *(h8*)&dst[(size_t)i * 8] = v;
}

// ---------------------------------------------------------------------------
// R8 resubmission (acquire-level infra failure: no timing fields; kernel
// audited deadlock/OOB/replay-safe). Fixes vs R7's measured stalls
// (230us/dispatch, MfmaUtil 9%, traffic already fixed):
//  1. BARRIER: 256-way fetch_add on ONE line = 8-15us/phase serialized LLC
//     RMWs. Dependency is only within a bt-group (64 blocks), so: per-(bt,g)
//     sub-counters (4x8, own 128B lines, 8 adds each); wave-0 lanes poll the
//     8 sub-counters of their bt in PARALLEL. Monotone targets -> safe under
//     rocprof replay.
//  2. UNIFIED PHASE PIPELINE: l0+l1 merged into ONE 33-A-chunk K-loop.
//     h1(t-1) chunks are consumed TWICE while LDS-resident (Whh0->acc_l0 AND
//     Wih1->acc_l1): A-loads 49->33, one prologue/phase instead of two,
//     continuous MFMA flow. Same 196 MFMAs/wave/phase.
//     ca=0: x(t)->acc0 | ca 1..16: h1(t-1)->acc0+acc1 | ca 17..32: h2(t-2)->acc1.
//     Boundary phases (t==0 / t==S_) run the full loop on safe clamped
//     addresses and discard the dead layer's results in the epilogue.
// Everything else (NT streams, LLC h-exchange, ring, relaxed atomics, W
// register pipeline 3-ahead, A window double buffer) unchanged from R7.
// ---------------------------------------------------------------------------

__global__ __launch_bounds__(512, 2)
void k_mphase(int tbeg, int tcnt, unsigned int* __restrict__ cnt,
              const half_t* __restrict__ x_h,
              const half_t* __restrict__ Wih0, const half_t* __restrict__ Whh0,
              const float* __restrict__ bias0, float* __restrict__ c1g, half_t* __restrict__ h1r,
              const half_t* __restrict__ Wih1, const half_t* __restrict__ Whh1,
              const float* __restrict__ bias1, float* __restrict__ c2g, half_t* __restrict__ h2r,
              const float* __restrict__ fcW, float* __restrict__ out_part)
{
    // A double buffer: 2 windows x 4 chunks x 9216B = 73728 B.
    // Epilogue union: gs0 17408 | gs1 17408 | h_s 4352 | fcw 1536 = 40704 B.
    __shared__ __align__(16) char smraw[73728];
    half_t* A_s   = (half_t*)smraw;
    float*  gs0   = (float*)smraw;                   // [4][64*17]
    float*  gs1   = (float*)(smraw + 17408);         // [4][64*17]
    float*  h_s   = (float*)(smraw + 34816);         // [64*17]
    float*  fcw_s = (float*)(smraw + 39168);         // [24*16]

    const int n   = blockIdx.x;
    const int htp = (n & 7) + 8 * ((n >> 3) & 7);    // htp%8 == n%8 (XCD-resident W)
    const int g8  = (n >> 3) & 7;                    // barrier sub-group
    const int bt  = (n >> 6) & 3;
    const int thr = threadIdx.x;
    const int wave = thr >> 6, lane = thr & 63;
    const int gate = wave >> 1, mh = wave & 1;
    const int quad = lane >> 4, l15 = lane & 15;
    const int ar = thr >> 3;             // A staging row 0..63
    const int ak = (thr & 7) * 8;        // A staging k-offset (halfs)
    const int ghW = gate * 32 + (htp >> 1);
    const int jo  = (htp & 1) * 2;       // fragment col-half select

    // persistent per-launch state; c NT load/store once per launch
    const int erow = thr >> 3, ecp = thr & 7;
    const int ec0 = 2 * ecp;
    const size_t cb = (size_t)(bt * 64 + erow) * H_ + htp * 16 + ec0;
    float c1e = __builtin_nontemporal_load(&c1g[cb]);
    float c1o = __builtin_nontemporal_load(&c1g[cb + 1]);
    float c2e = __builtin_nontemporal_load(&c2g[cb]);
    float c2o = __builtin_nontemporal_load(&c2g[cb + 1]);
    float fp0 = 0.f, fp1 = 0.f, fp2 = 0.f;
    const float bv0 = bias0[gate * H_ + htp * 16 + l15];
    const float bv1 = bias1[gate * H_ + htp * 16 + l15];

    for (int p = 0; p < tcnt; ++p) {
        const int t  = tbeg + p;
        const int tt = (t > 0) ? t - 1 : 0;
        const half_t* xb  = x_h + (size_t)((t < S_) ? t : S_ - 1) * F_;   // clamped (t==S_ discarded)
        const half_t* h1p = h1r + (size_t)((t + RING_ - 1) % RING_) * B_ * H_;
        const half_t* h2p = h2r + (size_t)((t + RING_ - 2 + RING_) % RING_) * B_ * H_;
        half_t* h1w = h1r + (size_t)(t % RING_) * B_ * H_;
        half_t* h2w = h2r + (size_t)(tt % RING_) * B_ * H_;

        f4 acc00 = (f4){bv0, bv0, bv0, bv0}, acc01 = acc00;   // l0 rows mh*32+0..15 / +16..31
        f4 acc10 = (f4){bv1, bv1, bv1, bv1}, acc11 = acc10;   // l1

        // A chunk ca: 0 -> x(t); 1..16 -> h1(t-1); 17..32 -> h2(t-2). NT loads.
        auto loadA = [&](int ca) -> f4 {
            const half_t* Ab; int lda, k0;
            if (ca == 0)      { Ab = xb;  lda = S_ * F_; k0 = 0; }
            else if (ca < 17) { Ab = h1p; lda = H_;      k0 = (ca - 1) * 64; }
            else              { Ab = h2p; lda = H_;      k0 = (ca - 17) * 64; }
            return __builtin_nontemporal_load(
                (const f4*)&Ab[(size_t)(bt * 64 + ar) * lda + k0 + ak]);
        };
        // W for chunk ca: r0,r1 = l0-or-l1 primary; r2,r3 = Wih1 (dual range only)
        auto fetchW = [&](int ca, h8& r0, h8& r1, h8& r2, h8& r3) {
            if (ca == 0) {
                const half_t* b0 = Wih0 + ((size_t)(ghW * 4 + jo) * 64 + lane) * 8;
                r0 = *(const h8*)(b0 + 0 * 512);
                r1 = *(const h8*)(b0 + 1 * 512);
            } else if (ca < 17) {
                const half_t* b0 = Whh0 + ((size_t)((ghW * 16 + (ca - 1)) * 4 + jo) * 64 + lane) * 8;
                r0 = *(const h8*)(b0 + 0 * 512);
                r1 = *(const h8*)(b0 + 1 * 512);
                const half_t* b1 = Wih1 + ((size_t)((ghW * 16 + (ca - 1)) * 4 + jo) * 64 + lane) * 8;
                r2 = *(const h8*)(b1 + 0 * 512);
                r3 = *(const h8*)(b1 + 1 * 512);
            } else {
                const half_t* b0 = Whh1 + ((size_t)((ghW * 16 + (ca - 17)) * 4 + jo) * 64 + lane) * 8;
                r0 = *(const h8*)(b0 + 0 * 512);
                r1 = *(const h8*)(b0 + 1 * 512);
            }
        };

        // ---- prologue: window 0 (ca 0..3) + pending (ca 4..7) + W 0..2 ----
        h8 W0a,W0b,W0c,W0d, W1a,W1b,W1c,W1d, W2a,W2b,W2c,W2d, W3a,W3b,W3c,W3d;
        f4 p0, p1, p2, p3;
        f4 a0_ = loadA(0), a1_ = loadA(1), a2_ = loadA(2), a3_ = loadA(3);
        p0 = loadA(4); p1 = loadA(5); p2 = loadA(6); p3 = loadA(7);
        fetchW(0, W0a, W0b, W0c, W0d);
        fetchW(1, W1a, W1b, W1c, W1d);
        fetchW(2, W2a, W2b, W2c, W2d);

        float fpre = 0.f;
        if (t > 0 && thr < 384)
            fpre = __builtin_nontemporal_load(
                &fcW[(size_t)tt * H_ + (size_t)(thr >> 4) * (S_ * H_) + htp * 16 + (thr & 15)]);

        *(f4*)&A_s[0 * 4608 + ar * 72 + ak] = a0_;
        *(f4*)&A_s[1 * 4608 + ar * 72 + ak] = a1_;
        *(f4*)&A_s[2 * 4608 + ar * 72 + ak] = a2_;
        *(f4*)&A_s[3 * 4608 + ar * 72 + ak] = a3_;
        __syncthreads();   // window 0 visible

        const int nA = 33;
        for (int s = 0; s < nA; s += 4) {
            const int rem = nA - s;
            const int ns = rem < 4 ? rem : 4;
            int ns2 = rem - 4; if (ns2 < 0) ns2 = 0; if (ns2 > 4) ns2 = 4;
            const int bufo = ((s >> 2) & 1) * 18432;
            const int obuf = 18432 - bufo;

            if (ns2 > 0) p0 = loadA(s + 4);
            if (ns2 > 1) p1 = loadA(s + 5);
            if (ns2 > 2) p2 = loadA(s + 6);
            if (ns2 > 3) p3 = loadA(s + 7);

            // STEP: chunk ca=s+i; l0 side if ca<17 (r0,r1); l1 side if ca>=17
            // (r0,r1) or dual 1..16 (r2,r3). Uniform branches.
            #define STEP(i, C0,C1,C2,C3, N0,N1,N2,N3)                                              \
            if (i < ns) {                                                                          \
                const int ca = s + i;                                                              \
                if (ca + 3 < nA) fetchW(ca + 3, N0, N1, N2, N3);                                   \
                h8 a0 = *(const h8*)&A_s[bufo + i * 4608 + (mh * 32 + l15) * 72 + quad * 8];       \
                h8 a1 = *(const h8*)&A_s[bufo + i * 4608 + (mh * 32 + 16 + l15) * 72 + quad * 8];  \
                h8 a2 = *(const h8*)&A_s[bufo + i * 4608 + (mh * 32 + l15) * 72 + 32 + quad * 8];  \
                h8 a3 = *(const h8*)&A_s[bufo + i * 4608 + (mh * 32 + 16 + l15) * 72 + 32 + quad * 8]; \
                if (ca < 17) {                                                                     \
                    acc00 = __builtin_amdgcn_mfma_f32_16x16x32_f16(a0, C0, acc00, 0, 0, 0);        \
                    acc01 = __builtin_amdgcn_mfma_f32_16x16x32_f16(a1, C0, acc01, 0, 0, 0);        \
                    acc00 = __builtin_amdgcn_mfma_f32_16x16x32_f16(a2, C1, acc00, 0, 0, 0);        \
                    acc01 = __builtin_amdgcn_mfma_f32_16x16x32_f16(a3, C1, acc01, 0, 0, 0);        \
                }                                                                                  \
                if (ca >= 17) {                                                                    \
                    acc10 = __builtin_amdgcn_mfma_f32_16x16x32_f16(a0, C0, acc10, 0, 0, 0);        \
                    acc11 = __builtin_amdgcn_mfma_f32_16x16x32_f16(a1, C0, acc11, 0, 0, 0);        \
                    acc10 = __builtin_amdgcn_mfma_f32_16x16x32_f16(a2, C1, acc10, 0, 0, 0);        \
                    acc11 = __builtin_amdgcn_mfma_f32_16x16x32_f16(a3, C1, acc11, 0, 0, 0);        \
                } else if (ca >= 1) {                                                              \
                    acc10 = __builtin_amdgcn_mfma_f32_16x16x32_f16(a0, C2, acc10, 0, 0, 0);        \
                    acc11 = __builtin_amdgcn_mfma_f32_16x16x32_f16(a1, C2, acc11, 0, 0, 0);        \
                    acc10 = __builtin_amdgcn_mfma_f32_16x16x32_f16(a2, C3, acc10, 0, 0, 0);        \
                    acc11 = __builtin_amdgcn_mfma_f32_16x16x32_f16(a3, C3, acc11, 0, 0, 0);        \
                }                                                                                  \
            }
            STEP(0, W0a,W0b,W0c,W0d, W3a,W3b,W3c,W3d)
            STEP(1, W1a,W1b,W1c,W1d, W0a,W0b,W0c,W0d)
            STEP(2, W2a,W2b,W2c,W2d, W1a,W1b,W1c,W1d)
            STEP(3, W3a,W3b,W3c,W3d, W2a,W2b,W2c,W2d)
            #undef STEP

            if (ns2 > 0) {
                /*always*/       *(f4*)&A_s[obuf + 0 * 4608 + ar * 72 + ak] = p0;
                if (ns2 > 1)     *(f4*)&A_s[obuf + 1 * 4608 + ar * 72 + ak] = p1;
                if (ns2 > 2)     *(f4*)&A_s[obuf + 2 * 4608 + ar * 72 + ak] = p2;
                if (ns2 > 3)     *(f4*)&A_s[obuf + 3 * 4608 + ar * 72 + ak] = p3;
                __syncthreads();
            }
        }
        __syncthreads();   // K-loop done; A_s reusable for epilogue

        // scatter both gate sets (C/D layout: col=lane&15, row=quad*4+reg)
        #pragma unroll
        for (int r = 0; r < 4; ++r) {
            gs0[gate * (64 * 17) + (mh * 32 + quad * 4 + r) * 17 + l15]      = acc00[r];
            gs0[gate * (64 * 17) + (mh * 32 + 16 + quad * 4 + r) * 17 + l15] = acc01[r];
            gs1[gate * (64 * 17) + (mh * 32 + quad * 4 + r) * 17 + l15]      = acc10[r];
            gs1[gate * (64 * 17) + (mh * 32 + 16 + quad * 4 + r) * 17 + l15] = acc11[r];
        }
        __syncthreads();

        if (t < S_) {   // layer-0 cell update -> h1(t)
            float ge = gs0[0 * (64 * 17) + erow * 17 + ec0];
            float go_ = gs0[0 * (64 * 17) + erow * 17 + ec0 + 1];
            float fe = gs0[1 * (64 * 17) + erow * 17 + ec0];
            float fo = gs0[1 * (64 * 17) + erow * 17 + ec0 + 1];
            float gge = gs0[2 * (64 * 17) + erow * 17 + ec0];
            float ggo = gs0[2 * (64 * 17) + erow * 17 + ec0 + 1];
            float oe = gs0[3 * (64 * 17) + erow * 17 + ec0];
            float oo = gs0[3 * (64 * 17) + erow * 17 + ec0 + 1];
            float sie = 1.f / (1.f + __expf(-ge)),  sio = 1.f / (1.f + __expf(-go_));
            float sfe = 1.f / (1.f + __expf(-fe)),  sfo = 1.f / (1.f + __expf(-fo));
            float soe = 1.f / (1.f + __expf(-oe)),  soo = 1.f / (1.f + __expf(-oo));
            float cne = sfe * c1e + sie * tanhf(gge);
            float cno = sfo * c1o + sio * tanhf(ggo);
            c1e = cne; c1o = cno;
            union { half_t h[2]; unsigned int u; } cv;
            cv.h[0] = (half_t)(soe * tanhf(cne));
            cv.h[1] = (half_t)(soo * tanhf(cno));
            __hip_atomic_store((unsigned int*)&h1w[cb], cv.u,
                               __ATOMIC_RELAXED, __HIP_MEMORY_SCOPE_AGENT);
        }
        if (t > 0) {    // layer-1 cell update -> h2(t-1) + FC accumulate
            float ge = gs1[0 * (64 * 17) + erow * 17 + ec0];
            float go_ = gs1[0 * (64 * 17) + erow * 17 + ec0 + 1];
            float fe = gs1[1 * (64 * 17) + erow * 17 + ec0];
            float fo = gs1[1 * (64 * 17) + erow * 17 + ec0 + 1];
            float gge = gs1[2 * (64 * 17) + erow * 17 + ec0];
            float ggo = gs1[2 * (64 * 17) + erow * 17 + ec0 + 1];
            float oe = gs1[3 * (64 * 17) + erow * 17 + ec0];
            float oo = gs1[3 * (64 * 17) + erow * 17 + ec0 + 1];
            float sie = 1.f / (1.f + __expf(-ge)),  sio = 1.f / (1.f + __expf(-go_));
            float sfe = 1.f / (1.f + __expf(-fe)),  sfo = 1.f / (1.f + __expf(-fo));
            float soe = 1.f / (1.f + __expf(-oe)),  soo = 1.f / (1.f + __expf(-oo));
            float cne = sfe * c2e + sie * tanhf(gge);
            float cno = sfo * c2o + sio * tanhf(ggo);
            c2e = cne; c2o = cno;
            float hne = soe * tanhf(cne);
            float hno = soo * tanhf(cno);
            union { half_t h[2]; unsigned int u; } cv;
            cv.h[0] = (half_t)hne; cv.h[1] = (half_t)hno;
            __hip_atomic_store((unsigned int*)&h2w[cb], cv.u,
                               __ATOMIC_RELAXED, __HIP_MEMORY_SCOPE_AGENT);
            h_s[erow * 17 + ec0]     = hne;
            h_s[erow * 17 + ec0 + 1] = hno;
            if (thr < 384) fcw_s[thr] = fpre;
            __syncthreads();
            #pragma unroll
            for (int q = 0; q < 3; ++q) {
                int pp = thr + q * 512;
                int o = pp >> 6, bb = pp & 63;
                float s2 = 0.f;
                #pragma unroll
                for (int j = 0; j < 16; ++j)
                    s2 += h_s[bb * 17 + j] * fcw_s[o * 16 + j];
                if (q == 0) fp0 += s2; else if (q == 1) fp1 += s2; else fp2 += s2;
            }
        }

        // ---- hierarchical per-bt barrier: 8 adds per 128B line, parallel poll
        __syncthreads();   // drain: h-stores at LLC, LDS readers done
        if (thr < 64) {
            if (lane == 0)
                __hip_atomic_fetch_add(&cnt[(bt * 8 + g8) * 32], 1u,
                                       __ATOMIC_RELAXED, __HIP_MEMORY_SCOPE_AGENT);
            const unsigned int target = 8u * (unsigned)(t + 1);
            unsigned int* myc = &cnt[(bt * 8 + (lane & 7)) * 32];
            while (__hip_atomic_load(myc, __ATOMIC_RELAXED, __HIP_MEMORY_SCOPE_AGENT) < target)
                __builtin_amdgcn_s_sleep(2);
        }
        __syncthreads();
    }

    // write back persistent state (NT; launch boundary publishes)
    __builtin_nontemporal_store(c1e, &c1g[cb]);
    __builtin_nontemporal_store(c1o, &c1g[cb + 1]);
    __builtin_nontemporal_store(c2e, &c2g[cb]);
    __builtin_nontemporal_store(c2o, &c2g[cb + 1]);
    #pragma unroll
    for (int q = 0; q < 3; ++q) {
        int pp = thr + q * 512;
        int o = pp >> 6, bb = pp & 63;
        size_t oi = (size_t)htp * (B_ * O_) + (bt * 64 + bb) * O_ + o;
        float prev = __builtin_nontemporal_load(&out_part[oi]);
        __builtin_nontemporal_store(prev + (q == 0 ? fp0 : (q == 1 ? fp1 : fp2)),
                                    &out_part[oi]);
    }
}

__global__ void k_final(const float* __restrict__ out_part, const float* __restrict__ fcb,
                        float* __restrict__ out) {
    int i = blockIdx.x * blockDim.x + threadIdx.x;
    if (i >= B_ * O_) return;
    int o = i % O_;
    float s = fcb[o];
    for (int tl = 0; tl < NT_; ++tl) s += out_part[(size_t)tl * (B_ * O_) + i];
    out[i] = s;
}

extern "C" void kernel_launch(void* const* d_in, const int* in_sizes, int n_in,
                              void* d_out, int out_size, void* d_ws, size_t ws_size,
                              hipStream_t stream) {
    const float* x    = (const float*)d_in[0];
    const float* Wih0 = (const float*)d_in[1];
    const float* Whh0 = (const float*)d_in[2];
    const float* bih0 = (const float*)d_in[3];
    const float* bhh0 = (const float*)d_in[4];
    const float* Wih1 = (const float*)d_in[5];
    const float* Whh1 = (const float*)d_in[6];
    const float* bih1 = (const float*)d_in[7];
    const float* bhh1 = (const float*)d_in[8];
    const float* fcW  = (const float*)d_in[9];
    const float* fcb  = (const float*)d_in[10];

    char* ws = (char*)d_ws;
    half_t* h1r    = (half_t*)(ws + OFF_H1);
    half_t* h2r    = (half_t*)(ws + OFF_H2);
    float*  c1     = (float*)(ws + OFF_C1);
    float*  c2     = (float*)(ws + OFF_C2);
    float*  opart  = (float*)(ws + OFF_OP);
    unsigned int* cnt = (unsigned int*)(ws + OFF_CNT);
    float*  bias0  = (float*)(ws + OFF_BIAS0);
    float*  bias1  = (float*)(ws + OFF_BIAS1);
    half_t* x_h    = (half_t*)(ws + OFF_XH);
    half_t* wih0_p = (half_t*)(ws + OFF_WIH0);
    half_t* whh0_p = (half_t*)(ws + OFF_WHH0);
    half_t* wih1_p = (half_t*)(ws + OFF_WIH1);
    half_t* whh1_p = (half_t*)(ws + OFF_WHH1);

    // zero h rings + c states + FC partials + barrier counters
    hipMemsetAsync(d_ws, 0, ZBYTES, stream);

    k_bias<<<dim3((G_ + 255) / 256), dim3(256), 0, stream>>>(bih0, bhh0, bih1, bhh1, bias0, bias1);
    k_cvt<<<dim3(2048), dim3(256), 0, stream>>>(x, x_h, B_ * S_ * F_);
    k_pack<<<dim3(128),  dim3(256), 0, stream>>>(Wih0, wih0_p, 1);
    k_pack<<<dim3(2048), dim3(256), 0, stream>>>(Whh0, whh0_p, 16);
    k_pack<<<dim3(2048), dim3(256), 0, stream>>>(Wih1, wih1_p, 16);
    k_pack<<<dim3(2048), dim3(256), 0, stream>>>(Whh1, whh1_p, 16);

    for (int tb = 0; tb <= S_; tb += TPL_) {
        int tc = S_ + 1 - tb; if (tc > TPL_) tc = TPL_;
        k_mphase<<<dim3(256), dim3(512), 0, stream>>>(tb, tc, cnt, x_h,
                                                      wih0_p, whh0_p, bias0, c1, h1r,
                                                      wih1_p, whh1_p, bias1, c2, h2r,
                                                      fcW, opart);
    }
    k_final<<<dim3((B_ * O_ + 255) / 256), dim3(256), 0, stream>>>(opart, fcb, (float*)d_out);
}

// Round 10
// 9674.294 us; speedup vs baseline: 2.3702x; 2.3702x over previous
//
#include <hip/hip_runtime.h>
#include <hip/hip_fp16.h>

#define B_ 256
#define S_ 512
#define F_ 64
#define H_ 1024
#define O_ 24
#define G_ 4096  // 4*H
#define NT_ 64   // ht' tile count (16-col tiles)

typedef _Float16 half_t;
typedef _Float16 h8 __attribute__((ext_vector_type(8)));
typedef float f4 __attribute__((ext_vector_type(4)));

// ---- workspace layout (bytes) ----
#define OFF_H1 ((size_t)0)                                   // 2*B*H halfs (ping-pong)
#define OFF_H2 (OFF_H1 + (size_t)2*B_*H_*2)
#define OFF_C1 (OFF_H2 + (size_t)2*B_*H_*2)                  // B*H f32
#define OFF_C2 (OFF_C1 + (size_t)B_*H_*4)
#define OFF_OP (OFF_C2 + (size_t)B_*H_*4)                    // out_part [64][B][O] f32
#define ZBYTES (OFF_OP + (size_t)NT_*B_*O_*4)
#define OFF_BIAS0 (ZBYTES)
#define OFF_BIAS1 (OFF_BIAS0 + (size_t)G_*4)
#define OFF_XH    (OFF_BIAS1 + (size_t)G_*4)                 // B*S*F halfs
#define OFF_WIH0  (OFF_XH + (size_t)B_*S_*F_*2)              // packed, G*F halfs
#define OFF_WHH0  (OFF_WIH0 + (size_t)G_*F_*2)               // packed, G*H halfs
#define OFF_WIH1  (OFF_WHH0 + (size_t)G_*H_*2)
#define OFF_WHH1  (OFF_WIH1 + (size_t)G_*H_*2)
#define WS_NEEDED (OFF_WHH1 + (size_t)G_*H_*2)               // ~46 MiB

__global__ void k_bias(const float* __restrict__ bi0, const float* __restrict__ bh0,
                       const float* __restrict__ bi1, const float* __restrict__ bh1,
                       float* __restrict__ bias0, float* __restrict__ bias1) {
    int i = blockIdx.x * blockDim.x + threadIdx.x;
    if (i < G_) { bias0[i] = bi0[i] + bh0[i]; bias1[i] = bi1[i] + bh1[i]; }
}

__global__ void k_cvt(const float* __restrict__ src, half_t* __restrict__ dst, int n) {
    int i = blockIdx.x * blockDim.x + threadIdx.x;
    int stride = gridDim.x * blockDim.x;
    for (; i < n; i += stride) dst[i] = (half_t)src[i];
}

// Pack W [4H, NC*64] f32 -> fp16 MFMA-fragment order:
// dst h8 index i = (((g*32+ht)*NC + ck)*4 + j)*64 + lane, j = colhalf*2 + kshalf
__global__ void k_pack(const float* __restrict__ src, half_t* __restrict__ dst, int NC) {
    int i = blockIdx.x * blockDim.x + threadIdx.x;
    int total = 32768 * NC;          // 4*32*NC*4*64
    if (i >= total) return;
    int lane = i & 63;
    int j    = (i >> 6) & 3;
    int ck   = (i >> 8) % NC;
    int gh   = i / (256 * NC);       // g*32+ht, 0..127
    int srow = (gh >> 5) * H_ + (gh & 31) * 32 + (j >> 1) * 16 + (lane & 15);
    int scol = ck * 64 + (j & 1) * 32 + (lane >> 4) * 8;
    const float* s = src + (size_t)srow * (NC * 64) + scol;
    h8 v;
    #pragma unroll
    for (int e = 0; e < 8; ++e) v[e] = (half_t)s[e];
    *(h8*)&dst[(size_t)i * 8] = v;
}

// ---------------------------------------------------------------------------
// R10: back to the best-measured kernel (R4 structure, 9640us; merged-kernel
// family R6-R9 all slower, abandoned per R7 decision rule). ONE change:
// every __syncthreads in k_phase -> lgkmcnt(0)-only + raw s_barrier.
// Rationale [guide §5 m97-ceiling + T3/T4]: hipcc's __syncthreads emits
// s_waitcnt vmcnt(0) lgkmcnt(0) before s_barrier, draining the 3-ahead W
// register prefetches (issued 100-300cy before each window barrier) and the
// c/fcW epilogue prefetches -> one fresh L2/LLC latency per window, ~25-30
// barriers/phase. All intra-phase barriers only order LDS data (A windows,
// gate scatter, h_s/fcw_s) -> lgkmcnt(0) suffices; global prefetches keep
// their precise counted vmcnt waits at their register-dependent consumers.
// Global h/c stores are consumed only by the NEXT launch (launch boundary
// publishes). Merged-kernel counters support the theory: MfmaUtil ~9% ==
// exactly the 2.6us/phase MFMA floor; FETCH small; HBM 6% -> ~85% waitcnt.
// ---------------------------------------------------------------------------

__device__ __forceinline__ void bar_lds() {
    // LDS-visibility barrier WITHOUT vmcnt drain (keeps global prefetches live)
    asm volatile("s_waitcnt lgkmcnt(0)" ::: "memory");
    __builtin_amdgcn_s_barrier();
}

__device__ __forceinline__ void run_part(
    const int thr, const int bt, const int htp,
    const int cx, const int nchunks,
    const half_t* __restrict__ xb, const int ldx,
    const half_t* __restrict__ hp,
    const half_t* __restrict__ Wih, const half_t* __restrict__ Whh,
    const float* __restrict__ bias,
    float* __restrict__ c, half_t* __restrict__ hn_out,
    const float* __restrict__ fcWt, float* __restrict__ out_part,
    half_t* A_s, float* gate_s, float* h_s, float* fcw_s,
    const bool do_fc)
{
    const int wave = thr >> 6, lane = thr & 63;
    const int gate = wave >> 1, mh = wave & 1;
    const int quad = lane >> 4, l15 = lane & 15;
    const int ar = thr >> 3;             // A staging row 0..63
    const int ak = (thr & 7) * 8;        // A staging k-offset (halfs)
    const int ghW = gate * 32 + (htp >> 1);
    const int jo  = (htp & 1) * 2;       // fragment col-half select

    float bv = bias[gate * H_ + htp * 16 + l15];
    f4 acc0 = (f4){bv, bv, bv, bv};      // rows mh*32 + 0..15
    f4 acc1 = acc0;                      // rows mh*32 + 16..31

    auto loadA = [&](int ck) -> f4 {
        const half_t* Ab; int lda, k0;
        if (ck < cx) { Ab = xb; lda = ldx; k0 = ck * 64; }
        else         { Ab = hp; lda = H_;  k0 = (ck - cx) * 64; }
        return *(const f4*)&Ab[(size_t)(bt * 64 + ar) * lda + k0 + ak];
    };
    auto fetchW = [&](int ck, h8& r0, h8& r1) {
        const half_t* Wb; int ckk, NC;
        if (ck < cx) { Wb = Wih; ckk = ck;      NC = cx; }
        else         { Wb = Whh; ckk = ck - cx; NC = 16; }
        const half_t* base = Wb + ((size_t)(((ghW * NC) + ckk) * 4 + jo) * 64 + lane) * 8;
        r0 = *(const h8*)(base + 0 * 512);
        r1 = *(const h8*)(base + 1 * 512);
    };

    // ---- prologue: window 0 A loads + W chunks 0..2 ----
    h8 W0a,W0b, W1a,W1b, W2a,W2b, W3a,W3b;
    f4 p0, p1, p2, p3;
    f4 a0_ = loadA(0), a1_ = loadA(1), a2_ = loadA(2), a3_ = loadA(3);
    p0 = loadA(4); p1 = loadA(5); p2 = loadA(6); p3 = loadA(7);
    fetchW(0, W0a, W0b);
    fetchW(1, W1a, W1b);
    fetchW(2, W2a, W2b);

    // epilogue prefetches: this block is sole owner of its (b,h) slice this
    // phase, so c read now == c at epilogue; fcW slice is const + HBM-cold.
    // With bar_lds these stay in flight across the whole K-loop.
    const int eb = thr >> 4, ecol = thr & 15;
    const size_t cbase = (size_t)(bt * 64 + eb) * H_ + htp * 16 + ecol;
    float cpre0 = c[cbase];
    float cpre1 = c[cbase + (size_t)32 * H_];
    float fpre = 0.f;
    if (do_fc && thr < 384)
        fpre = fcWt[(size_t)(thr >> 4) * (S_ * H_) + htp * 16 + (thr & 15)];

    *(f4*)&A_s[0 * 4608 + ar * 72 + ak] = a0_;
    *(f4*)&A_s[1 * 4608 + ar * 72 + ak] = a1_;
    *(f4*)&A_s[2 * 4608 + ar * 72 + ak] = a2_;
    *(f4*)&A_s[3 * 4608 + ar * 72 + ak] = a3_;
    bar_lds();   // window 0 visible (W prefetches stay in flight)

    for (int s = 0; s < nchunks; s += 4) {
        const int rem = nchunks - s;
        const int ns = rem < 4 ? rem : 4;                 // block-uniform
        int ns2 = rem - 4; if (ns2 < 0) ns2 = 0; if (ns2 > 4) ns2 = 4;
        const int bufo = ((s >> 2) & 1) * 18432;          // read buffer (halfs)
        const int obuf = 18432 - bufo;                    // write buffer

        // issue NEXT window's A loads (latency hides under compute)
        if (ns2 > 0) p0 = loadA(s + 4);
        if (ns2 > 1) p1 = loadA(s + 5);
        if (ns2 > 2) p2 = loadA(s + 6);
        if (ns2 > 3) p3 = loadA(s + 7);

        // compute ns chunks; W pipeline 3 ahead (4 sets, chunk c -> set c&3)
        #define STEP(i, C0,C1, N0,N1)                                                          \
        if (i < ns) {                                                                          \
            if (s + i + 3 < nchunks) fetchW(s + i + 3, N0, N1);                                \
            h8 a0 = *(const h8*)&A_s[bufo + i * 4608 + (mh * 32 + l15) * 72 + quad * 8];       \
            h8 a1 = *(const h8*)&A_s[bufo + i * 4608 + (mh * 32 + 16 + l15) * 72 + quad * 8];  \
            h8 a2 = *(const h8*)&A_s[bufo + i * 4608 + (mh * 32 + l15) * 72 + 32 + quad * 8];  \
            h8 a3 = *(const h8*)&A_s[bufo + i * 4608 + (mh * 32 + 16 + l15) * 72 + 32 + quad * 8]; \
            acc0 = __builtin_amdgcn_mfma_f32_16x16x32_f16(a0, C0, acc0, 0, 0, 0);              \
            acc1 = __builtin_amdgcn_mfma_f32_16x16x32_f16(a1, C0, acc1, 0, 0, 0);              \
            acc0 = __builtin_amdgcn_mfma_f32_16x16x32_f16(a2, C1, acc0, 0, 0, 0);              \
            acc1 = __builtin_amdgcn_mfma_f32_16x16x32_f16(a3, C1, acc1, 0, 0, 0);              \
        }
        STEP(0, W0a,W0b, W3a,W3b)
        STEP(1, W1a,W1b, W0a,W0b)
        STEP(2, W2a,W2b, W1a,W1b)
        STEP(3, W3a,W3b, W2a,W2b)
        #undef STEP

        // store next window into the other buffer; ONE barrier per window.
        // ds_write waits p-loads via counted vmcnt (register dep) -- the
        // younger W prefetches stay in flight across bar_lds.
        if (ns2 > 0) {
            /*always*/       *(f4*)&A_s[obuf + 0 * 4608 + ar * 72 + ak] = p0;
            if (ns2 > 1)     *(f4*)&A_s[obuf + 1 * 4608 + ar * 72 + ak] = p1;
            if (ns2 > 2)     *(f4*)&A_s[obuf + 2 * 4608 + ar * 72 + ak] = p2;
            if (ns2 > 3)     *(f4*)&A_s[obuf + 3 * 4608 + ar * 72 + ak] = p3;
            bar_lds();
        }
    }
    bar_lds();   // all waves done reading A windows before LDS reuse

    // scatter gates (C/D layout: col=lane&15, row=quad*4+reg)
    #pragma unroll
    for (int r = 0; r < 4; ++r) {
        gate_s[gate * (64 * 17) + (mh * 32 + quad * 4 + r) * 17 + l15]      = acc0[r];
        gate_s[gate * (64 * 17) + (mh * 32 + 16 + quad * 4 + r) * 17 + l15] = acc1[r];
    }
    bar_lds();

    // cell update: 64x16 = 1024 (b,h) elems, 2/thread; c prefetched at start
    #pragma unroll
    for (int kk = 0; kk < 2; ++kk) {
        int b = eb + kk * 32;
        float gi = gate_s[0 * (64 * 17) + b * 17 + ecol];
        float gf = gate_s[1 * (64 * 17) + b * 17 + ecol];
        float gg = gate_s[2 * (64 * 17) + b * 17 + ecol];
        float go = gate_s[3 * (64 * 17) + b * 17 + ecol];
        float si = 1.f / (1.f + __expf(-gi));
        float sf = 1.f / (1.f + __expf(-gf));
        float so = 1.f / (1.f + __expf(-go));
        float tg = tanhf(gg);
        float cn = sf * (kk ? cpre1 : cpre0) + si * tg;
        size_t cidx = cbase + (size_t)kk * 32 * H_;
        c[cidx] = cn;
        float hnv = so * tanhf(cn);
        hn_out[cidx] = (half_t)hnv;
        if (do_fc) h_s[b * 17 + ecol] = hnv;
    }

    if (do_fc) {
        if (thr < 384) fcw_s[thr] = fpre;   // [24][16] staged from prefetch
        bar_lds();
        #pragma unroll
        for (int q = 0; q < 3; ++q) {
            int p = thr + q * 512;           // 0..1535 = 64b x 24o
            int o = p >> 6, bb = p & 63;
            float s2 = 0.f;
            #pragma unroll
            for (int j = 0; j < 16; ++j)
                s2 += h_s[bb * 17 + j] * fcw_s[o * 16 + j];
            out_part[(size_t)htp * (B_ * O_) + (bt * 64 + bb) * O_ + o] += s2;
        }
    }
    bar_lds();   // guard LDS reuse by the next part
}

__global__ __launch_bounds__(512, 2)
void k_phase(int t,
             const half_t* __restrict__ x_h,
             const half_t* __restrict__ Wih0, const half_t* __restrict__ Whh0,
             const float* __restrict__ bias0, float* __restrict__ c1g, half_t* __restrict__ h1buf,
             const half_t* __restrict__ Wih1, const half_t* __restrict__ Whh1,
             const float* __restrict__ bias1, float* __restrict__ c2g, half_t* __restrict__ h2buf,
             const float* __restrict__ fcW, float* __restrict__ out_part)
{
    // window-4 double-buffered A: 2 x [4][64*72] halfs = 73728 B (proven size)
    // epilogue LDS unioned on top (23296 B used)
    __shared__ __align__(16) char smraw[73728];
    half_t* A_s    = (half_t*)smraw;
    float*  gate_s = (float*)smraw;                  // [4][64*17] = 17408 B
    float*  h_s    = (float*)(smraw + 17408);        // [64*17]    =  4352 B
    float*  fcw_s  = (float*)(smraw + 21760);        // [24*16]    =  1536 B

    const int n   = blockIdx.x;
    const int htp = (n & 7) + 8 * ((n >> 3) & 7);    // htp % 8 == n % 8 (XCD-resident W)
    const int bt  = (n >> 6) & 3;
    const int thr = threadIdx.x;

    if (t < S_) {       // layer-0 part: h1(t) from x(t), h1(t-1)
        const int tt = t;
        run_part(thr, bt, htp, /*cx=*/1, /*nchunks=*/17,
                 x_h + (size_t)tt * F_, S_ * F_,
                 h1buf + (size_t)((tt - 1) & 1) * B_ * H_,
                 Wih0, Whh0, bias0, c1g,
                 h1buf + (size_t)(tt & 1) * B_ * H_,
                 nullptr, nullptr,
                 A_s, gate_s, h_s, fcw_s, false);
    }
    if (t > 0) {        // layer-1 part: h2(t-1) from h1(t-1), h2(t-2); + FC tail
        const int tt = t - 1;
        run_part(thr, bt, htp, /*cx=*/16, /*nchunks=*/32,
                 h1buf + (size_t)(tt & 1) * B_ * H_, H_,
                 h2buf + (size_t)((tt - 1) & 1) * B_ * H_,
                 Wih1, Whh1, bias1, c2g,
                 h2buf + (size_t)(tt & 1) * B_ * H_,
                 fcW + (size_t)tt * H_, out_part,
                 A_s, gate_s, h_s, fcw_s, true);
    }
}

__global__ void k_final(const float* __restrict__ out_part, const float* __restrict__ fcb,
                        float* __restrict__ out) {
    int i = blockIdx.x * blockDim.x + threadIdx.x;
    if (i >= B_ * O_) return;
    int o = i % O_;
    float s = fcb[o];
    for (int tl = 0; tl < NT_; ++tl) s += out_part[(size_t)tl * (B_ * O_) + i];
    out[i] = s;
}

extern "C" void kernel_launch(void* const* d_in, const int* in_sizes, int n_in,
                              void* d_out, int out_size, void* d_ws, size_t ws_size,
                              hipStream_t stream) {
    const float* x    = (const float*)d_in[0];
    const float* Wih0 = (const float*)d_in[1];
    const float* Whh0 = (const float*)d_in[2];
    const float* bih0 = (const float*)d_in[3];
    const float* bhh0 = (const float*)d_in[4];
    const float* Wih1 = (const float*)d_in[5];
    const float* Whh1 = (const float*)d_in[6];
    const float* bih1 = (const float*)d_in[7];
    const float* bhh1 = (const float*)d_in[8];
    const float* fcW  = (const float*)d_in[9];
    const float* fcb  = (const float*)d_in[10];

    char* ws = (char*)d_ws;
    half_t* h1buf  = (half_t*)(ws + OFF_H1);
    half_t* h2buf  = (half_t*)(ws + OFF_H2);
    float*  c1     = (float*)(ws + OFF_C1);
    float*  c2     = (float*)(ws + OFF_C2);
    float*  opart  = (float*)(ws + OFF_OP);
    float*  bias0  = (float*)(ws + OFF_BIAS0);
    float*  bias1  = (float*)(ws + OFF_BIAS1);
    half_t* x_h    = (half_t*)(ws + OFF_XH);
    half_t* wih0_p = (half_t*)(ws + OFF_WIH0);
    half_t* whh0_p = (half_t*)(ws + OFF_WHH0);
    half_t* wih1_p = (half_t*)(ws + OFF_WIH1);
    half_t* whh1_p = (half_t*)(ws + OFF_WHH1);

    // zero states + FC partials (ws poisoned 0xAA before every launch)
    hipMemsetAsync(d_ws, 0, ZBYTES, stream);

    k_bias<<<dim3((G_ + 255) / 256), dim3(256), 0, stream>>>(bih0, bhh0, bih1, bhh1, bias0, bias1);
    k_cvt<<<dim3(2048), dim3(256), 0, stream>>>(x, x_h, B_ * S_ * F_);
    k_pack<<<dim3(128),  dim3(256), 0, stream>>>(Wih0, wih0_p, 1);
    k_pack<<<dim3(2048), dim3(256), 0, stream>>>(Whh0, whh0_p, 16);
    k_pack<<<dim3(2048), dim3(256), 0, stream>>>(Wih1, wih1_p, 16);
    k_pack<<<dim3(2048), dim3(256), 0, stream>>>(Whh1, whh1_p, 16);

    dim3 grid(256), blk(512);
    for (int t = 0; t <= S_; ++t) {
        k_phase<<<grid, blk, 0, stream>>>(t, x_h,
                                          wih0_p, whh0_p, bias0, c1, h1buf,
                                          wih1_p, whh1_p, bias1, c2, h2buf,
                                          fcW, opart);
    }
    k_final<<<dim3((B_ * O_ + 255) / 256), dim3(256), 0, stream>>>(opart, fcb, (float*)d_out);
}